// Round 12
// baseline (5326.041 us; speedup 1.0000x reference)
//
#include <hip/hip_runtime.h>

typedef float f32x4 __attribute__((ext_vector_type(4)));
typedef short s16x8 __attribute__((ext_vector_type(8)));
typedef unsigned short u16;
typedef unsigned short u16x4 __attribute__((ext_vector_type(4)));
typedef unsigned short u16x8 __attribute__((ext_vector_type(8)));
typedef unsigned int u32x2 __attribute__((ext_vector_type(2)));

__device__ __forceinline__ float bf2f(u16 u){ union{unsigned int i; float f;} v; v.i=((unsigned int)u)<<16; return v.f; }
__device__ __forceinline__ u16 f2bf(float f){ union{float f; unsigned int i;} v; v.f=f; return (u16)((v.i + 0x7FFFu + ((v.i>>16)&1u))>>16); }
__device__ __forceinline__ float aexp2(float x){ float r; asm("v_exp_f32 %0, %1" : "=v"(r) : "v"(x)); return r; }
__device__ __forceinline__ unsigned int cvtpk(float lo, float hi){ unsigned int r; asm("v_cvt_pk_bf16_f32 %0, %1, %2" : "=v"(r) : "v"(lo), "v"(hi)); return r; }

#define LOG2E 1.44269504089f

__device__ __forceinline__ void gld16(const void* gp, void* lp){
  __builtin_amdgcn_global_load_lds((__attribute__((address_space(1))) void*)(void*)gp,
                                   (__attribute__((address_space(3))) void*)lp, 16, 0, 0);
}

// job mapping: XCD-chunked + 2D super-tile (SRxSC), ks outermost
__device__ __forceinline__ void job_map(int bid, int gridx, int nrt, int nct, int ksplit,
                                        int SR, int SC, int& rt, int& ct, int& ks){
  int jpx = gridx >> 3;
  int wgid = (bid & 7)*jpx + (bid >> 3);
  int nj1 = nrt*nct;
  ks = wgid / nj1; int rr = wgid - ks*nj1;
  int spc = SR*SC, nstc = nct/SC;
  int st = rr / spc, win = rr - st*spc;
  int str_ = st / nstc, stc = st - str_*nstc;
  int wr = win / SC, wc = win - wr*SC;
  rt = str_*SR + wr;
  ct = stc*SC + wc;
}

// ---------------- embed gather ----------------
__global__ __launch_bounds__(256) void k_embed(const int* __restrict__ ids, const float* __restrict__ emb, float* __restrict__ x){
  int r = blockIdx.x;
  int id = ids[r];
  const f32x4* src = (const f32x4*)(emb + (size_t)id*1536);
  f32x4* dst = (f32x4*)(x + (size_t)r*1536);
  for (int i = threadIdx.x; i < 384; i += 256) dst[i] = src[i];
}

// ---------------- mask -> additive bf16 table ----------------
__global__ __launch_bounds__(256) void k_mask(const float* __restrict__ mask, u16* __restrict__ mtab){
  int i = blockIdx.x*256 + threadIdx.x;
  float mv = mask[i];
  mtab[i] = (mv==0.f) ? f2bf(-1.4e9f) : f2bf(-4.f*LOG2E);
}

// ---------------- RMSNorm ----------------
__global__ __launch_bounds__(256) void k_rms(const float* __restrict__ x, const float* __restrict__ w, u16* __restrict__ h){
  int r = blockIdx.x, tid = threadIdx.x;
  const f32x4* xr = (const f32x4*)(x + (size_t)r*1536);
  f32x4 v0 = xr[tid];
  float ss = v0.x*v0.x + v0.y*v0.y + v0.z*v0.z + v0.w*v0.w;
  f32x4 v1 = {0,0,0,0};
  if (tid < 128){ v1 = xr[256+tid]; ss += v1.x*v1.x + v1.y*v1.y + v1.z*v1.z + v1.w*v1.w; }
  #pragma unroll
  for (int off=32; off; off>>=1) ss += __shfl_xor(ss, off, 64);
  __shared__ float red[4];
  if ((tid&63)==0) red[tid>>6] = ss;
  __syncthreads();
  float tot = red[0]+red[1]+red[2]+red[3];
  float invr = rsqrtf(tot*(1.f/1536.f) + 1e-6f);
  const f32x4* w4 = (const f32x4*)w;
  u16x4* h4 = (u16x4*)(h + (size_t)r*1536);
  {
    f32x4 wv = w4[tid];
    u16x4 o; o.x=f2bf(v0.x*invr*wv.x); o.y=f2bf(v0.y*invr*wv.y); o.z=f2bf(v0.z*invr*wv.z); o.w=f2bf(v0.w*invr*wv.w);
    h4[tid] = o;
  }
  if (tid < 128){
    f32x4 wv = w4[256+tid];
    u16x4 o; o.x=f2bf(v1.x*invr*wv.x); o.y=f2bf(v1.y*invr*wv.y); o.z=f2bf(v1.z*invr*wv.z); o.w=f2bf(v1.w*invr*wv.w);
    h4[256+tid] = o;
  }
}

// ---------------- fused: x += P ; h = rms(x)*w ----------------
__global__ __launch_bounds__(256) void k_rms_add(float* __restrict__ x, const float* __restrict__ P, const float* __restrict__ w, u16* __restrict__ h){
  int r = blockIdx.x, tid = threadIdx.x;
  f32x4* xr = (f32x4*)(x + (size_t)r*1536);
  const f32x4* pr = (const f32x4*)(P + (size_t)r*1536);
  f32x4 v0 = xr[tid], p0 = pr[tid];
  v0.x+=p0.x; v0.y+=p0.y; v0.z+=p0.z; v0.w+=p0.w;
  xr[tid] = v0;
  float ss = v0.x*v0.x + v0.y*v0.y + v0.z*v0.z + v0.w*v0.w;
  f32x4 v1 = {0,0,0,0};
  if (tid < 128){
    v1 = xr[256+tid]; f32x4 p1 = pr[256+tid];
    v1.x+=p1.x; v1.y+=p1.y; v1.z+=p1.z; v1.w+=p1.w;
    xr[256+tid] = v1;
    ss += v1.x*v1.x + v1.y*v1.y + v1.z*v1.z + v1.w*v1.w;
  }
  #pragma unroll
  for (int off=32; off; off>>=1) ss += __shfl_xor(ss, off, 64);
  __shared__ float red[4];
  if ((tid&63)==0) red[tid>>6] = ss;
  __syncthreads();
  float tot = red[0]+red[1]+red[2]+red[3];
  float invr = rsqrtf(tot*(1.f/1536.f) + 1e-6f);
  const f32x4* w4 = (const f32x4*)w;
  u16x4* h4 = (u16x4*)(h + (size_t)r*1536);
  {
    f32x4 wv = w4[tid];
    u16x4 o; o.x=f2bf(v0.x*invr*wv.x); o.y=f2bf(v0.y*invr*wv.y); o.z=f2bf(v0.z*invr*wv.z); o.w=f2bf(v0.w*invr*wv.w);
    h4[tid] = o;
  }
  if (tid < 128){
    f32x4 wv = w4[256+tid];
    u16x4 o; o.x=f2bf(v1.x*invr*wv.x); o.y=f2bf(v1.y*invr*wv.y); o.z=f2bf(v1.z*invr*wv.z); o.w=f2bf(v1.w*invr*wv.w);
    h4[256+tid] = o;
  }
}

// ---------------- transpose+convert fp32(K,N) -> bf16(N,K) ----------------
__device__ __forceinline__ void cvt_tile(const float* src, int K, int N, u16* dst, int k0, int n0, int roff, int mode){
  __shared__ float T[64*72];
  int tid = threadIdx.x;
  #pragma unroll
  for (int j=0;j<4;++j){
    int i = tid + j*256;
    int row = i>>4, nf = i&15;
    f32x4 vv = *(const f32x4*)(src + (size_t)(k0+row)*N + n0 + nf*4);
    *(f32x4*)&T[row*72 + nf*4] = vv;
  }
  __syncthreads();
  #pragma unroll
  for (int j=0;j<2;++j){
    int i = tid + j*256;
    int n = i>>3, kc = i&7;
    u16x8 o;
    #pragma unroll
    for (int m=0;m<8;++m) o[m] = f2bf(T[(kc*8+m)*72 + n]);
    int gn = n0 + n;
    int dr = (mode==0) ? (roff + gn) : (((gn>>4)<<5) + ((mode==2)?16:0) + (gn&15));
    *(u16x8*)(dst + (size_t)dr*K + k0 + kc*8) = o;
  }
}

__global__ __launch_bounds__(256) void k_cvt_layer(
  const float* __restrict__ Wq, const float* __restrict__ Wk, const float* __restrict__ Wv,
  const float* __restrict__ Wo, const float* __restrict__ Wg, const float* __restrict__ Wu,
  const float* __restrict__ Wd, u16* qkvt, u16* wot, u16* gut, u16* wdt)
{
  const float* src; int K, N; u16* dst; int roff=0, mode=0;
  switch (blockIdx.y){
    case 0: src=Wq; K=1536; N=1536; dst=qkvt; break;
    case 1: src=Wk; K=1536; N=256;  dst=qkvt; roff=1536; break;
    case 2: src=Wv; K=1536; N=256;  dst=qkvt; roff=1792; break;
    case 3: src=Wo; K=1536; N=1536; dst=wot;  break;
    case 4: src=Wg; K=1536; N=8960; dst=gut;  mode=1; break;
    case 5: src=Wu; K=1536; N=8960; dst=gut;  mode=2; break;
    default: src=Wd; K=8960; N=1536; dst=wdt; break;
  }
  int ntn = N>>6;
  int nt = (K>>6)*ntn;
  int t = blockIdx.x;
  if (t >= nt) return;
  cvt_tile(src, K, N, dst, (t/ntn)<<6, (t%ntn)<<6, roff, mode);
}

__global__ __launch_bounds__(256) void k_cvt_one(const float* __restrict__ src, u16* __restrict__ dst){
  int t = blockIdx.x;
  cvt_tile(src, 1536, 1536, dst, (t/24)<<6, (t%24)<<6, 0, 0);
}

// ---------------- 128^2 GEMM, BK=32, 3-buffer prefetch-2 counted-vmcnt (48KB LDS -> 3 blocks/CU) ----------------
#define MODE_QKV 0
#define MODE_WO 1
#define MODE_GATEUP 2
#define MODE_DOWN 3
#define MODE_W1 4

template<int MODE>
__global__ __launch_bounds__(256) void k_gemm(
  const u16* __restrict__ A, const u16* __restrict__ Bt, int K,
  int nrt, int nct, int ksplit, int klen, int SR, int SC,
  const float* __restrict__ bq_, const float* __restrict__ bk_, const float* __restrict__ bv_,
  float* __restrict__ xio, float* __restrict__ Pf,
  const float* __restrict__ cosT, const float* __restrict__ sinT,
  u16* __restrict__ o0, u16* __restrict__ o1, u16* __restrict__ o2)
{
  int rt, ct, ks;
  job_map(blockIdx.x, gridDim.x, nrt, nct, ksplit, SR, SC, rt, ct, ks);
  int kbase = ks*klen;
  int nt = klen >> 5;

  __shared__ __align__(16) u16 As[3][4096], Bs[3][4096];   // 48 KiB total
  int tid = threadIdx.x;
  int lane = tid & 63, w = tid >> 6;
  int wr = w >> 1, wc = w & 1;
  int row0 = rt * 128, col0 = ct * 128;
  int l15 = lane & 15, l4 = lane >> 4;
  f32x4 acc[4][4] = {};
  const u16* aBase = A + (size_t)row0*K;
  const u16* bBase = Bt + (size_t)col0*K;
  int rr0 = tid & 127, kb0 = tid >> 7;
  int kb1 = kb0 + 2;

  auto stage = [&](int bf, int kt){
    gld16(aBase + (size_t)rr0*K + kt + kb0*8, &As[bf][tid*8]);
    gld16(bBase + (size_t)rr0*K + kt + kb0*8, &Bs[bf][tid*8]);
    gld16(aBase + (size_t)rr0*K + kt + kb1*8, &As[bf][(256+tid)*8]);
    gld16(bBase + (size_t)rr0*K + kt + kb1*8, &Bs[bf][(256+tid)*8]);
  };
  // prologue: 2 tiles in flight
  stage(0, kbase); stage(1, kbase+32);

  int bf = 0;
  for (int t = 0; t < nt; ++t){
    // wait tile t landed; tile t+1 (4 loads) may stay in flight
    if (t < nt-1) asm volatile("s_waitcnt vmcnt(4)" ::: "memory");
    else          asm volatile("s_waitcnt vmcnt(0)" ::: "memory");
    __builtin_amdgcn_s_barrier();
    __builtin_amdgcn_sched_barrier(0);
    if (t+2 < nt){
      int nb = bf+2; if (nb >= 3) nb -= 3;
      stage(nb, kbase + (t+2)*32);     // buffer (t-1)%3: reads retired before this barrier
    }
    const u16* Ab = As[bf];
    const u16* Bb = Bs[bf];
    s16x8 af[4], bf_[4];
    #pragma unroll
    for (int i=0;i<4;++i) af[i]  = *(const s16x8*)&Ab[((l4<<7) + wr*64 + i*16 + l15)*8];
    #pragma unroll
    for (int jj=0;jj<4;++jj) bf_[jj] = *(const s16x8*)&Bb[((l4<<7) + wc*64 + jj*16 + l15)*8];
    __builtin_amdgcn_s_setprio(1);
    #pragma unroll
    for (int i=0;i<4;++i)
      #pragma unroll
      for (int jj=0;jj<4;++jj)
        acc[i][jj] = __builtin_amdgcn_mfma_f32_16x16x32_bf16(af[i], bf_[jj], acc[i][jj], 0, 0, 0);
    __builtin_amdgcn_s_setprio(0);
    if (++bf == 3) bf = 0;
  }

  #pragma unroll
  for (int i=0;i<4;++i)
    #pragma unroll
    for (int jj=0;jj<4;++jj)
      #pragma unroll
      for (int r=0;r<4;++r){
        int row = row0 + wr*64 + i*16 + l4*4 + r;
        int c   = col0 + wc*64 + jj*16 + l15;
        float v = acc[i][jj][r];
        if constexpr (MODE == MODE_QKV){
          int b = row >> 11, s = row & 2047;
          if (c < 1536){
            int d = c & 63, hd = c >> 6;
            float vv = v + bq_[c];
            float pv = acc[i][jj^2][r] + bq_[c^32];
            float cv = cosT[s*64+d], sv = sinT[s*64+d];
            float sgn = (d<32) ? -1.f : 1.f;
            float o = (vv*cv + sgn*pv*sv)*(0.125f*LOG2E);
            o0[(size_t)(b*24+hd)*131072 + (size_t)(s>>6)*4096
               + (s&63)*64 + (((d>>3)^(s&7))<<3) + (d&7)] = f2bf(o);
          } else if (c < 1792){
            int c2 = c - 1536, d = c2 & 63, kv = c2 >> 6;
            float vv = v + bk_[c2];
            float pv = acc[i][jj^2][r] + bk_[c2^32];
            float cv = cosT[s*64+d], sv = sinT[s*64+d];
            float sgn = (d<32) ? -1.f : 1.f;
            float o = vv*cv + sgn*pv*sv;
            o1[(size_t)(b*4+kv)*131072 + (size_t)(s>>6)*4096
               + (s&63)*64 + (((d>>3)^(s&7))<<3) + (d&7)] = f2bf(o);
          } else {
            int c2 = c - 1792, d = c2 & 63, kv = c2 >> 6;
            float vv = v + bv_[c2];
            o2[(size_t)(b*4+kv)*131072 + (size_t)(s>>6)*4096
               + d*64 + ((((s>>3)&7)^(d&7))<<3) + (s&7)] = f2bf(vv);
          }
        } else if constexpr (MODE == MODE_WO){
          xio[(size_t)row*1536 + c] += v;
        } else if constexpr (MODE == MODE_W1){
          v += bq_[c];
          float ge = 0.5f * v * (1.f + erff(v * 0.70710678118f));
          o0[(size_t)row*1536 + c] = f2bf(ge);
        }
      }
}

// ---------------- 256^2 GEMM: fine 4-phase/tile schedule (round-11, kept) ----------------
template<int MODE>
__global__ __launch_bounds__(512,2) void k_gemm256(
  const u16* __restrict__ A, const u16* __restrict__ Bt, int K,
  int nrt, int nct, int ksplit, int klen, int SR, int SC,
  float* __restrict__ xio, float* __restrict__ Pf, u16* __restrict__ o0)
{
  int rt, ct, ks;
  job_map(blockIdx.x, gridDim.x, nrt, nct, ksplit, SR, SC, rt, ct, ks);

  __shared__ __align__(16) u16 lds[2][2][16384];
  int tid = threadIdx.x;
  int lane = tid & 63, wid = tid >> 6;
  int wm = wid >> 2, wn = wid & 3;
  int l15 = lane & 15, l4 = lane >> 4;
  int lsw = l15 & 7;
  int row0 = rt*256, col0 = ct*256;
  int kbase = ks*klen*64;

  const u16* aB = A  + (size_t)row0*K + kbase;
  const u16* bB = Bt + (size_t)col0*K + kbase;
  int rsub = tid >> 3;
  int gsw  = (lane & 7) ^ ((lane >> 3) & 7);

  f32x4 acc[8][4] = {};

  auto sgA = [&](int bf, int kt, int c){
    gld16(aB + (size_t)(c*64 + rsub)*K + kt*64 + gsw*8, &lds[bf][0][(c*512+tid)*8]);
  };
  auto sgB = [&](int bf, int kt, int c){
    gld16(bB + (size_t)(c*64 + rsub)*K + kt*64 + gsw*8, &lds[bf][1][(c*512+tid)*8]);
  };

  sgB(0,0,0); sgB(0,0,1); sgB(0,0,2); sgB(0,0,3);
  sgA(0,0,0); sgA(0,0,2); sgA(0,0,1); sgA(0,0,3);

  for (int t = 0; t < klen; ++t){
    int b = t & 1, nb = b ^ 1;
    bool hn = (t+1 < klen);
    const u16* Ab = lds[b][0];
    const u16* Bb = lds[b][1];
    s16x8 bfr[4][2];

    asm volatile("s_waitcnt vmcnt(2)" ::: "memory");
    __builtin_amdgcn_s_barrier();
    __builtin_amdgcn_sched_barrier(0);
    {
      s16x8 af[2][2];
      #pragma unroll
      for (int ii=0;ii<2;++ii)
        #pragma unroll
        for (int ksu=0;ksu<2;++ksu)
          af[ii][ksu] = *(const s16x8*)&Ab[(wm*128 + ii*16 + l15)*64 + (((ksu*4+l4)^lsw)<<3)];
      #pragma unroll
      for (int j=0;j<4;++j)
        #pragma unroll
        for (int ksu=0;ksu<2;++ksu)
          bfr[j][ksu] = *(const s16x8*)&Bb[(wn*64 + j*16 + l15)*64 + (((ksu*4+l4)^lsw)<<3)];
      if (hn){ sgB(nb, t+1, 0); sgB(nb, t+1, 1); }
      asm volatile("s_waitcnt lgkmcnt(0)" ::: "memory");
      __builtin_amdgcn_sched_barrier(0);
      __builtin_amdgcn_s_setprio(1);
      #pragma unroll
      for (int ii=0;ii<2;++ii)
        #pragma unroll
        for (int j=0;j<4;++j)
          #pragma unroll
          for (int ksu=0;ksu<2;++ksu)
            acc[ii][j] = __builtin_amdgcn_mfma_f32_16x16x32_bf16(af[ii][ksu], bfr[j][ksu], acc[ii][j], 0,0,0);
      __builtin_amdgcn_s_setprio(0);
      __builtin_amdgcn_s_barrier();
    }
    {
      s16x8 af[2][2];
      #pragma unroll
      for (int ii=0;ii<2;++ii)
        #pragma unroll
        for (int ksu=0;ksu<2;++ksu)
          af[ii][ksu] = *(const s16x8*)&Ab[(wm*128 + 32 + ii*16 + l15)*64 + (((ksu*4+l4)^lsw)<<3)];
      if (hn){ sgB(nb, t+1, 2); sgB(nb, t+1, 3); }
      asm volatile("s_waitcnt lgkmcnt(0)" ::: "memory");
      __builtin_amdgcn_sched_barrier(0);
      __builtin_amdgcn_s_setprio(1);
      #pragma unroll
      for (int ii=0;ii<2;++ii)
        #pragma unroll
        for (int j=0;j<4;++j)
          #pragma unroll
          for (int ksu=0;ksu<2;++ksu)
            acc[2+ii][j] = __builtin_amdgcn_mfma_f32_16x16x32_bf16(af[ii][ksu], bfr[j][ksu], acc[2+ii][j], 0,0,0);
      __builtin_amdgcn_s_setprio(0);
      __builtin_amdgcn_s_barrier();
    }
    if (hn) asm volatile("s_waitcnt vmcnt(4)" ::: "memory");
    else    asm volatile("s_waitcnt vmcnt(0)" ::: "memory");
    __builtin_amdgcn_s_barrier();
    __builtin_amdgcn_sched_barrier(0);
    {
      s16x8 af[2][2];
      #pragma unroll
      for (int ii=0;ii<2;++ii)
        #pragma unroll
        for (int ksu=0;ksu<2;++ksu)
          af[ii][ksu] = *(const s16x8*)&Ab[(wm*128 + 64 + ii*16 + l15)*64 + (((ksu*4+l4)^lsw)<<3)];
      if (hn){ sgA(nb, t+1, 0); sgA(nb, t+1, 2); }
      asm volatile("s_waitcnt lgkmcnt(0)" ::: "memory");
      __builtin_amdgcn_sched_barrier(0);
      __builtin_amdgcn_s_setprio(1);
      #pragma unroll
      for (int ii=0;ii<2;++ii)
        #pragma unroll
        for (int j=0;j<4;++j)
          #pragma unroll
          for (int ksu=0;ksu<2;++ksu)
            acc[4+ii][j] = __builtin_amdgcn_mfma_f32_16x16x32_bf16(af[ii][ksu], bfr[j][ksu], acc[4+ii][j], 0,0,0);
      __builtin_amdgcn_s_setprio(0);
      __builtin_amdgcn_s_barrier();
    }
    {
      s16x8 af[2][2];
      #pragma unroll
      for (int ii=0;ii<2;++ii)
        #pragma unroll
        for (int ksu=0;ksu<2;++ksu)
          af[ii][ksu] = *(const s16x8*)&Ab[(wm*128 + 96 + ii*16 + l15)*64 + (((ksu*4+l4)^lsw)<<3)];
      if (hn){ sgA(nb, t+1, 1); sgA(nb, t+1, 3); }
      asm volatile("s_waitcnt lgkmcnt(0)" ::: "memory");
      __builtin_amdgcn_sched_barrier(0);
      __builtin_amdgcn_s_setprio(1);
      #pragma unroll
      for (int ii=0;ii<2;++ii)
        #pragma unroll
        for (int j=0;j<4;++j)
          #pragma unroll
          for (int ksu=0;ksu<2;++ksu)
            acc[6+ii][j] = __builtin_amdgcn_mfma_f32_16x16x32_bf16(af[ii][ksu], bfr[j][ksu], acc[6+ii][j], 0,0,0);
      __builtin_amdgcn_s_setprio(0);
      __builtin_amdgcn_s_barrier();
    }
  }

  if constexpr (MODE == MODE_GATEUP){
    #pragma unroll
    for (int i=0;i<8;++i)
      #pragma unroll
      for (int j2=0;j2<4;j2+=2)
        #pragma unroll
        for (int r=0;r<4;++r){
          int row = row0 + wm*128 + i*16 + l4*4 + r;
          int cp  = col0 + wn*64 + j2*16 + l15;
          float gv = acc[i][j2][r], uv = acc[i][j2+1][r];
          float sg = 1.f/(1.f + __expf(-gv));
          int n = ((cp>>5)<<4) + (cp&15);
          o0[(size_t)row*8960 + n] = f2bf(sg*uv);
        }
  } else {
    #pragma unroll
    for (int i=0;i<8;++i)
      #pragma unroll
      for (int j=0;j<4;++j)
        #pragma unroll
        for (int r=0;r<4;++r){
          int row = row0 + wm*128 + i*16 + l4*4 + r;
          int c   = col0 + wn*64 + j*16 + l15;
          float v = acc[i][j][r];
          if (ks == 0) Pf[(size_t)row*1536 + c] = v;
          else         xio[(size_t)row*1536 + c] += v;
        }
  }
}

// ---------------- flash attention: 40KB LDS, global mask table, exp2, cvt_pk ----------------
__global__ __launch_bounds__(256) void k_attn(
  const u16* __restrict__ q, const u16* __restrict__ k, const u16* __restrict__ v,
  const u16* __restrict__ mtab, u16* __restrict__ attn)
{
  __shared__ __align__(16) u16 Qs[4096];
  __shared__ __align__(16) u16 Kd[2][4096];
  __shared__ __align__(16) u16 Vd[2][4096];
  int tid = threadIdx.x;
  int lane = tid & 63, w = tid >> 6;
  int qb = blockIdx.x;
  int bh = blockIdx.y;
  int b = bh / 24, hh = bh % 24, kv = hh / 6;
  int l15 = lane & 15, l4 = lane >> 4;
  int sw = l15 & 7;

  const u16* qhead = q + ((size_t)(b*24 + hh))*131072 + qb*4096;
  const u16* khead = k + ((size_t)(b*4  + kv))*131072;
  const u16* vhead = v + ((size_t)(b*4  + kv))*131072;
  const u16* mrow = mtab + b*2048;

  gld16(qhead + tid*8,       &Qs[tid*8]);
  gld16(qhead + (256+tid)*8, &Qs[(256+tid)*8]);

  auto stage = [&](int bf, int kt){
    gld16(khead + kt*4096 + tid*8,       &Kd[bf][tid*8]);
    gld16(khead + kt*4096 + (256+tid)*8, &Kd[bf][(256+tid)*8]);
    gld16(vhead + kt*4096 + tid*8,       &Vd[bf][tid*8]);
    gld16(vhead + kt*4096 + (256+tid)*8, &Vd[bf][(256+tid)*8]);
  };
  stage(0, 0);

  s16x8 aq0, aq1;
  f32x4 oacc[4] = {};
  float lsum = 0.f;
  u16* Pw = &Qs[w*1024];

  for (int t = 0; t < 32; ++t){
    asm volatile("s_waitcnt vmcnt(0)" ::: "memory");
    __builtin_amdgcn_s_barrier();
    __builtin_amdgcn_sched_barrier(0);
    if (t == 0){
      int qrow = w*16 + l15;
      aq0 = *(const s16x8*)&Qs[qrow*64 + (( l4    ^ sw)<<3)];
      aq1 = *(const s16x8*)&Qs[qrow*64 + (((4+l4) ^ sw)<<3)];
    }
    if (t+1 < 32) stage((t+1)&1, t+1);
    const u16* Kb = Kd[t&1];
    const u16* Vb = Vd[t&1];
    f32x4 sk[4] = {};
    __builtin_amdgcn_s_setprio(1);
    #pragma unroll
    for (int kn=0; kn<4; ++kn){
      int krow = kn*16 + l15;
      s16x8 a0 = *(const s16x8*)&Kb[krow*64 + (( l4    ^ sw)<<3)];
      s16x8 a1 = *(const s16x8*)&Kb[krow*64 + (((4+l4) ^ sw)<<3)];
      sk[kn] = __builtin_amdgcn_mfma_f32_16x16x32_bf16(a0, aq0, sk[kn], 0,0,0);
      sk[kn] = __builtin_amdgcn_mfma_f32_16x16x32_bf16(a1, aq1, sk[kn], 0,0,0);
    }
    __builtin_amdgcn_s_setprio(0);
    #pragma unroll
    for (int kn=0; kn<4; ++kn){
      u16x4 mv = *(const u16x4*)&mrow[t*64 + kn*16 + l4*4];
      float p0 = aexp2(sk[kn][0] + bf2f(mv.x));
      float p1 = aexp2(sk[kn][1] + bf2f(mv.y));
      float p2 = aexp2(sk[kn][2] + bf2f(mv.z));
      float p3 = aexp2(sk[kn][3] + bf2f(mv.w));
      lsum += (p0 + p1) + (p2 + p3);
      u32x2 pk; pk.x = cvtpk(p0, p1); pk.y = cvtpk(p2, p3);
      int g = kn*2 + (l4>>1);
      *(u32x2*)&Pw[l15*64 + ((g ^ sw)<<3) + (l4&1)*4] = pk;
    }
    __builtin_amdgcn_s_setprio(1);
    #pragma unroll
    for (int ksu=0; ksu<2; ++ksu){
      s16x8 ap = *(const s16x8*)&Pw[l15*64 + (((ksu*4+l4) ^ sw)<<3)];
      #pragma unroll
      for (int dg=0; dg<4; ++dg){
        s16x8 bv = *(const s16x8*)&Vb[(dg*16+l15)*64 + (((ksu*4+l4) ^ sw)<<3)];
        oacc[dg] = __builtin_amdgcn_mfma_f32_16x16x32_bf16(ap, bv, oacc[dg], 0,0,0);
      }
    }
    __builtin_amdgcn_s_setprio(0);
  }
  lsum += __shfl_xor(lsum, 16, 64);
  lsum += __shfl_xor(lsum, 32, 64);
  float invq[4];
  #pragma unroll
  for (int r=0;r<4;++r) invq[r] = 1.f / __shfl(lsum, l4*4 + r, 64);
  #pragma unroll
  for (int dg=0;dg<4;++dg)
    #pragma unroll
    for (int r=0;r<4;++r){
      int token = b*2048 + qb*64 + w*16 + l4*4 + r;
      int col = hh*64 + dg*16 + l15;
      attn[(size_t)token*1536 + col] = f2bf(oacc[dg][r] * invq[r]);
    }
}

// ---------------- final GEMV ----------------
__global__ __launch_bounds__(256) void k_gemv(const u16* __restrict__ h2, const float* __restrict__ W2, const float* __restrict__ b2, float* __restrict__ out){
  int tid = threadIdx.x, lane = tid & 63, w = tid >> 6;
  int r = blockIdx.x*4 + w;
  const u16* hr = h2 + (size_t)r*1536;
  float s = 0.f;
  #pragma unroll
  for (int i=0;i<24;++i){ int c = lane + i*64; s += bf2f(hr[c]) * W2[c]; }
  #pragma unroll
  for (int off=32; off; off>>=1) s += __shfl_xor(s, off, 64);
  if (lane == 0) out[r] = s + b2[0];
}

extern "C" void kernel_launch(void* const* d_in, const int* in_sizes, int n_in,
                              void* d_out, int out_size, void* d_ws, size_t ws_size,
                              hipStream_t stream)
{
  const int*   ids   = (const int*)d_in[0];
  const float* mask  = (const float*)d_in[1];
  const float* embed = (const float*)d_in[2];
  const float* Wq    = (const float*)d_in[3];
  const float* bq    = (const float*)d_in[4];
  const float* Wk    = (const float*)d_in[5];
  const float* bk    = (const float*)d_in[6];
  const float* Wv    = (const float*)d_in[7];
  const float* bv    = (const float*)d_in[8];
  const float* Wo    = (const float*)d_in[9];
  const float* ln1   = (const float*)d_in[10];
  const float* ln2   = (const float*)d_in[11];
  const float* Wg    = (const float*)d_in[12];
  const float* Wu    = (const float*)d_in[13];
  const float* Wd    = (const float*)d_in[14];
  const float* nw    = (const float*)d_in[15];
  const float* W1    = (const float*)d_in[16];
  const float* b1    = (const float*)d_in[17];
  const float* W2    = (const float*)d_in[18];
  const float* b2    = (const float*)d_in[19];
  const float* cosT  = (const float*)d_in[20];
  const float* sinT  = (const float*)d_in[21];

  char* ws = (char*)d_ws;
  float* x   = (float*)(ws + 0);            // 4096x1536 f32
  u16* h     = (u16*)(ws + 25165824);       // 4096x1536 bf16
  u16* qb_   = (u16*)(ws + 37748736);       // (2,24) heads x 131072 u16, tiled+swizzled
  u16* kb_   = (u16*)(ws + 50331648);       // (2,4) kv-heads x 131072 u16, tiled+swizzled
  u16* vb_   = (u16*)(ws + 52428800);       // (2,4) kv-heads x 131072 u16, V^T tiled+swizzled
  u16* attn  = (u16*)(ws + 54525952);       // 4096x1536 bf16 (also final gelu h2)
  u16* g     = (u16*)(ws + 67108864);       // 4096x8960 bf16
  u16* qkvt  = (u16*)(ws + 140509184);      // 2048x1536 bf16
  u16* wot   = (u16*)(ws + 146800640);      // 1536x1536 bf16
  u16* gut   = (u16*)(ws + 151519232);      // 17920x1536 bf16
  u16* wdt   = (u16*)(ws + 206569472);      // 1536x8960 bf16
  u16* mtab  = (u16*)(ws + 234094592);      // 2x2048 bf16 additive mask
  float* Pf  = (float*)(ws + 37748736);     // down split-K partial (overlays q/k/v/attn, dead then)
  (void)in_sizes; (void)n_in; (void)out_size; (void)ws_size;

  k_embed<<<4096, 256, 0, stream>>>(ids, embed, x);
  k_mask<<<16, 256, 0, stream>>>(mask, mtab);
  for (int l = 0; l < 8; ++l){
    k_cvt_layer<<<dim3(3360,7), 256, 0, stream>>>(
      Wq + (size_t)l*1536*1536, Wk + (size_t)l*1536*256, Wv + (size_t)l*1536*256,
      Wo + (size_t)l*1536*1536, Wg + (size_t)l*1536*8960, Wu + (size_t)l*1536*8960,
      Wd + (size_t)l*8960*1536, qkvt, wot, gut, wdt);
    if (l == 0) k_rms<<<4096, 256, 0, stream>>>(x, ln1, h);
    else        k_rms_add<<<4096, 256, 0, stream>>>(x, Pf, ln1 + l*1536, h);
    k_gemm<MODE_QKV><<<512, 256, 0, stream>>>(h, qkvt, 1536, 32, 16, 1, 1536, 8, 4,
        bq + l*1536, bk + l*256, bv + l*256, nullptr, nullptr, cosT, sinT, qb_, kb_, vb_);
    k_attn<<<dim3(32,48), 256, 0, stream>>>(qb_, kb_, vb_, mtab, attn);
    k_gemm<MODE_WO><<<384, 256, 0, stream>>>(attn, wot, 1536, 32, 12, 1, 1536, 8, 4,
        nullptr, nullptr, nullptr, x, nullptr, nullptr, nullptr, nullptr, nullptr, nullptr);
    k_rms<<<4096, 256, 0, stream>>>(x, ln2 + l*1536, h);
    k_gemm256<MODE_GATEUP><<<1120, 512, 0, stream>>>(h, gut, 1536, 16, 70, 1, 24, 8, 10,
        nullptr, nullptr, g);
    k_gemm256<MODE_DOWN><<<192, 512, 0, stream>>>(g, wdt, 8960, 16, 6, 2, 70, 4, 6,
        x, Pf, nullptr);
  }
  k_cvt_one<<<576, 256, 0, stream>>>(W1, wot);
  k_rms_add<<<4096, 256, 0, stream>>>(x, Pf, nw, h);
  k_gemm<MODE_W1><<<384, 256, 0, stream>>>(h, wot, 1536, 32, 12, 1, 1536, 8, 4,
      b1, nullptr, nullptr, nullptr, nullptr, nullptr, nullptr, attn, nullptr, nullptr);
  k_gemv<<<1024, 256, 0, stream>>>(attn, W2, b2, (float*)d_out);
}

// Round 13
// 5128.203 us; speedup vs baseline: 1.0386x; 1.0386x over previous
//
#include <hip/hip_runtime.h>

typedef float f32x4 __attribute__((ext_vector_type(4)));
typedef short s16x8 __attribute__((ext_vector_type(8)));
typedef unsigned short u16;
typedef unsigned short u16x4 __attribute__((ext_vector_type(4)));
typedef unsigned short u16x8 __attribute__((ext_vector_type(8)));
typedef unsigned int u32x2 __attribute__((ext_vector_type(2)));

__device__ __forceinline__ float bf2f(u16 u){ union{unsigned int i; float f;} v; v.i=((unsigned int)u)<<16; return v.f; }
__device__ __forceinline__ u16 f2bf(float f){ union{float f; unsigned int i;} v; v.f=f; return (u16)((v.i + 0x7FFFu + ((v.i>>16)&1u))>>16); }
__device__ __forceinline__ float aexp2(float x){ float r; asm("v_exp_f32 %0, %1" : "=v"(r) : "v"(x)); return r; }
__device__ __forceinline__ unsigned int cvtpk(float lo, float hi){ unsigned int r; asm("v_cvt_pk_bf16_f32 %0, %1, %2" : "=v"(r) : "v"(lo), "v"(hi)); return r; }

#define LOG2E 1.44269504089f

__device__ __forceinline__ void gld16(const void* gp, void* lp){
  __builtin_amdgcn_global_load_lds((__attribute__((address_space(1))) void*)(void*)gp,
                                   (__attribute__((address_space(3))) void*)lp, 16, 0, 0);
}

// job mapping: XCD-chunked + 2D super-tile (SRxSC), ks outermost
__device__ __forceinline__ void job_map(int bid, int gridx, int nrt, int nct, int ksplit,
                                        int SR, int SC, int& rt, int& ct, int& ks){
  int jpx = gridx >> 3;
  int wgid = (bid & 7)*jpx + (bid >> 3);
  int nj1 = nrt*nct;
  ks = wgid / nj1; int rr = wgid - ks*nj1;
  int spc = SR*SC, nstc = nct/SC;
  int st = rr / spc, win = rr - st*spc;
  int str_ = st / nstc, stc = st - str_*nstc;
  int wr = win / SC, wc = win - wr*SC;
  rt = str_*SR + wr;
  ct = stc*SC + wc;
}

// ---------------- embed gather ----------------
__global__ __launch_bounds__(256) void k_embed(const int* __restrict__ ids, const float* __restrict__ emb, float* __restrict__ x){
  int r = blockIdx.x;
  int id = ids[r];
  const f32x4* src = (const f32x4*)(emb + (size_t)id*1536);
  f32x4* dst = (f32x4*)(x + (size_t)r*1536);
  for (int i = threadIdx.x; i < 384; i += 256) dst[i] = src[i];
}

// ---------------- mask -> additive bf16 table ----------------
__global__ __launch_bounds__(256) void k_mask(const float* __restrict__ mask, u16* __restrict__ mtab){
  int i = blockIdx.x*256 + threadIdx.x;
  float mv = mask[i];
  mtab[i] = (mv==0.f) ? f2bf(-1.4e9f) : f2bf(-4.f*LOG2E);
}

// ---------------- RMSNorm ----------------
__global__ __launch_bounds__(256) void k_rms(const float* __restrict__ x, const float* __restrict__ w, u16* __restrict__ h){
  int r = blockIdx.x, tid = threadIdx.x;
  const f32x4* xr = (const f32x4*)(x + (size_t)r*1536);
  f32x4 v0 = xr[tid];
  float ss = v0.x*v0.x + v0.y*v0.y + v0.z*v0.z + v0.w*v0.w;
  f32x4 v1 = {0,0,0,0};
  if (tid < 128){ v1 = xr[256+tid]; ss += v1.x*v1.x + v1.y*v1.y + v1.z*v1.z + v1.w*v1.w; }
  #pragma unroll
  for (int off=32; off; off>>=1) ss += __shfl_xor(ss, off, 64);
  __shared__ float red[4];
  if ((tid&63)==0) red[tid>>6] = ss;
  __syncthreads();
  float tot = red[0]+red[1]+red[2]+red[3];
  float invr = rsqrtf(tot*(1.f/1536.f) + 1e-6f);
  const f32x4* w4 = (const f32x4*)w;
  u16x4* h4 = (u16x4*)(h + (size_t)r*1536);
  {
    f32x4 wv = w4[tid];
    u16x4 o; o.x=f2bf(v0.x*invr*wv.x); o.y=f2bf(v0.y*invr*wv.y); o.z=f2bf(v0.z*invr*wv.z); o.w=f2bf(v0.w*invr*wv.w);
    h4[tid] = o;
  }
  if (tid < 128){
    f32x4 wv = w4[256+tid];
    u16x4 o; o.x=f2bf(v1.x*invr*wv.x); o.y=f2bf(v1.y*invr*wv.y); o.z=f2bf(v1.z*invr*wv.z); o.w=f2bf(v1.w*invr*wv.w);
    h4[256+tid] = o;
  }
}

// ---------------- fused: x += P ; h = rms(x)*w ----------------
__global__ __launch_bounds__(256) void k_rms_add(float* __restrict__ x, const float* __restrict__ P, const float* __restrict__ w, u16* __restrict__ h){
  int r = blockIdx.x, tid = threadIdx.x;
  f32x4* xr = (f32x4*)(x + (size_t)r*1536);
  const f32x4* pr = (const f32x4*)(P + (size_t)r*1536);
  f32x4 v0 = xr[tid], p0 = pr[tid];
  v0.x+=p0.x; v0.y+=p0.y; v0.z+=p0.z; v0.w+=p0.w;
  xr[tid] = v0;
  float ss = v0.x*v0.x + v0.y*v0.y + v0.z*v0.z + v0.w*v0.w;
  f32x4 v1 = {0,0,0,0};
  if (tid < 128){
    v1 = xr[256+tid]; f32x4 p1 = pr[256+tid];
    v1.x+=p1.x; v1.y+=p1.y; v1.z+=p1.z; v1.w+=p1.w;
    xr[256+tid] = v1;
    ss += v1.x*v1.x + v1.y*v1.y + v1.z*v1.z + v1.w*v1.w;
  }
  #pragma unroll
  for (int off=32; off; off>>=1) ss += __shfl_xor(ss, off, 64);
  __shared__ float red[4];
  if ((tid&63)==0) red[tid>>6] = ss;
  __syncthreads();
  float tot = red[0]+red[1]+red[2]+red[3];
  float invr = rsqrtf(tot*(1.f/1536.f) + 1e-6f);
  const f32x4* w4 = (const f32x4*)w;
  u16x4* h4 = (u16x4*)(h + (size_t)r*1536);
  {
    f32x4 wv = w4[tid];
    u16x4 o; o.x=f2bf(v0.x*invr*wv.x); o.y=f2bf(v0.y*invr*wv.y); o.z=f2bf(v0.z*invr*wv.z); o.w=f2bf(v0.w*invr*wv.w);
    h4[tid] = o;
  }
  if (tid < 128){
    f32x4 wv = w4[256+tid];
    u16x4 o; o.x=f2bf(v1.x*invr*wv.x); o.y=f2bf(v1.y*invr*wv.y); o.z=f2bf(v1.z*invr*wv.z); o.w=f2bf(v1.w*invr*wv.w);
    h4[256+tid] = o;
  }
}

// ---------------- transpose+convert fp32(K,N) -> bf16(N,K) ----------------
__device__ __forceinline__ void cvt_tile(const float* src, int K, int N, u16* dst, int k0, int n0, int roff, int mode){
  __shared__ float T[64*72];
  int tid = threadIdx.x;
  #pragma unroll
  for (int j=0;j<4;++j){
    int i = tid + j*256;
    int row = i>>4, nf = i&15;
    f32x4 vv = *(const f32x4*)(src + (size_t)(k0+row)*N + n0 + nf*4);
    *(f32x4*)&T[row*72 + nf*4] = vv;
  }
  __syncthreads();
  #pragma unroll
  for (int j=0;j<2;++j){
    int i = tid + j*256;
    int n = i>>3, kc = i&7;
    u16x8 o;
    #pragma unroll
    for (int m=0;m<8;++m) o[m] = f2bf(T[(kc*8+m)*72 + n]);
    int gn = n0 + n;
    int dr = (mode==0) ? (roff + gn) : (((gn>>4)<<5) + ((mode==2)?16:0) + (gn&15));
    *(u16x8*)(dst + (size_t)dr*K + k0 + kc*8) = o;
  }
}

__global__ __launch_bounds__(256) void k_cvt_layer(
  const float* __restrict__ Wq, const float* __restrict__ Wk, const float* __restrict__ Wv,
  const float* __restrict__ Wo, const float* __restrict__ Wg, const float* __restrict__ Wu,
  const float* __restrict__ Wd, u16* qkvt, u16* wot, u16* gut, u16* wdt)
{
  const float* src; int K, N; u16* dst; int roff=0, mode=0;
  switch (blockIdx.y){
    case 0: src=Wq; K=1536; N=1536; dst=qkvt; break;
    case 1: src=Wk; K=1536; N=256;  dst=qkvt; roff=1536; break;
    case 2: src=Wv; K=1536; N=256;  dst=qkvt; roff=1792; break;
    case 3: src=Wo; K=1536; N=1536; dst=wot;  break;
    case 4: src=Wg; K=1536; N=8960; dst=gut;  mode=1; break;
    case 5: src=Wu; K=1536; N=8960; dst=gut;  mode=2; break;
    default: src=Wd; K=8960; N=1536; dst=wdt; break;
  }
  int ntn = N>>6;
  int nt = (K>>6)*ntn;
  int t = blockIdx.x;
  if (t >= nt) return;
  cvt_tile(src, K, N, dst, (t/ntn)<<6, (t%ntn)<<6, roff, mode);
}

__global__ __launch_bounds__(256) void k_cvt_one(const float* __restrict__ src, u16* __restrict__ dst){
  int t = blockIdx.x;
  cvt_tile(src, 1536, 1536, dst, (t/24)<<6, (t%24)<<6, 0, 0);
}

// ---------------- 128^2 GEMM, BK=32, 3-buffer prefetch-2 counted-vmcnt ----------------
#define MODE_QKV 0
#define MODE_WO 1
#define MODE_GATEUP 2
#define MODE_DOWN 3
#define MODE_W1 4

template<int MODE>
__global__ __launch_bounds__(256) void k_gemm(
  const u16* __restrict__ A, const u16* __restrict__ Bt, int K,
  int nrt, int nct, int ksplit, int klen, int SR, int SC,
  const float* __restrict__ bq_, const float* __restrict__ bk_, const float* __restrict__ bv_,
  float* __restrict__ xio, float* __restrict__ Pf,
  const float* __restrict__ cosT, const float* __restrict__ sinT,
  u16* __restrict__ o0, u16* __restrict__ o1, u16* __restrict__ o2)
{
  int rt, ct, ks;
  job_map(blockIdx.x, gridDim.x, nrt, nct, ksplit, SR, SC, rt, ct, ks);
  int kbase = ks*klen;
  int nt = klen >> 5;

  __shared__ __align__(16) u16 As[3][4096], Bs[3][4096];
  int tid = threadIdx.x;
  int lane = tid & 63, w = tid >> 6;
  int wr = w >> 1, wc = w & 1;
  int row0 = rt * 128, col0 = ct * 128;
  int l15 = lane & 15, l4 = lane >> 4;
  f32x4 acc[4][4] = {};
  const u16* aBase = A + (size_t)row0*K;
  const u16* bBase = Bt + (size_t)col0*K;
  int rr0 = tid & 127, kb0 = tid >> 7;
  int kb1 = kb0 + 2;

  auto stage = [&](int bf, int kt){
    gld16(aBase + (size_t)rr0*K + kt + kb0*8, &As[bf][tid*8]);
    gld16(bBase + (size_t)rr0*K + kt + kb0*8, &Bs[bf][tid*8]);
    gld16(aBase + (size_t)rr0*K + kt + kb1*8, &As[bf][(256+tid)*8]);
    gld16(bBase + (size_t)rr0*K + kt + kb1*8, &Bs[bf][(256+tid)*8]);
  };
  stage(0, kbase); stage(1, kbase+32);

  int bf = 0;
  for (int t = 0; t < nt; ++t){
    if (t < nt-1) asm volatile("s_waitcnt vmcnt(4)" ::: "memory");
    else          asm volatile("s_waitcnt vmcnt(0)" ::: "memory");
    __builtin_amdgcn_s_barrier();
    __builtin_amdgcn_sched_barrier(0);
    if (t+2 < nt){
      int nb = bf+2; if (nb >= 3) nb -= 3;
      stage(nb, kbase + (t+2)*32);
    }
    const u16* Ab = As[bf];
    const u16* Bb = Bs[bf];
    s16x8 af[4], bf_[4];
    #pragma unroll
    for (int i=0;i<4;++i) af[i]  = *(const s16x8*)&Ab[((l4<<7) + wr*64 + i*16 + l15)*8];
    #pragma unroll
    for (int jj=0;jj<4;++jj) bf_[jj] = *(const s16x8*)&Bb[((l4<<7) + wc*64 + jj*16 + l15)*8];
    __builtin_amdgcn_s_setprio(1);
    #pragma unroll
    for (int i=0;i<4;++i)
      #pragma unroll
      for (int jj=0;jj<4;++jj)
        acc[i][jj] = __builtin_amdgcn_mfma_f32_16x16x32_bf16(af[i], bf_[jj], acc[i][jj], 0, 0, 0);
    __builtin_amdgcn_s_setprio(0);
    if (++bf == 3) bf = 0;
  }

  #pragma unroll
  for (int i=0;i<4;++i)
    #pragma unroll
    for (int jj=0;jj<4;++jj)
      #pragma unroll
      for (int r=0;r<4;++r){
        int row = row0 + wr*64 + i*16 + l4*4 + r;
        int c   = col0 + wc*64 + jj*16 + l15;
        float v = acc[i][jj][r];
        if constexpr (MODE == MODE_QKV){
          int b = row >> 11, s = row & 2047;
          if (c < 1536){
            int d = c & 63, hd = c >> 6;
            float vv = v + bq_[c];
            float pv = acc[i][jj^2][r] + bq_[c^32];
            float cv = cosT[s*64+d], sv = sinT[s*64+d];
            float sgn = (d<32) ? -1.f : 1.f;
            float o = (vv*cv + sgn*pv*sv)*(0.125f*LOG2E);
            o0[(size_t)(b*24+hd)*131072 + (size_t)(s>>6)*4096
               + (s&63)*64 + (((d>>3)^(s&7))<<3) + (d&7)] = f2bf(o);
          } else if (c < 1792){
            int c2 = c - 1536, d = c2 & 63, kv = c2 >> 6;
            float vv = v + bk_[c2];
            float pv = acc[i][jj^2][r] + bk_[c2^32];
            float cv = cosT[s*64+d], sv = sinT[s*64+d];
            float sgn = (d<32) ? -1.f : 1.f;
            float o = vv*cv + sgn*pv*sv;
            o1[(size_t)(b*4+kv)*131072 + (size_t)(s>>6)*4096
               + (s&63)*64 + (((d>>3)^(s&7))<<3) + (d&7)] = f2bf(o);
          } else {
            int c2 = c - 1792, d = c2 & 63, kv = c2 >> 6;
            float vv = v + bv_[c2];
            o2[(size_t)(b*4+kv)*131072 + (size_t)(s>>6)*4096
               + d*64 + ((((s>>3)&7)^(d&7))<<3) + (s&7)] = f2bf(vv);
          }
        } else if constexpr (MODE == MODE_WO){
          xio[(size_t)row*1536 + c] += v;
        } else if constexpr (MODE == MODE_W1){
          v += bq_[c];
          float ge = 0.5f * v * (1.f + erff(v * 0.70710678118f));
          o0[(size_t)row*1536 + c] = f2bf(ge);
        }
      }
}

// ---------------- 256^2 GEMM: fine 4-phase/tile schedule (round-11, kept) ----------------
template<int MODE>
__global__ __launch_bounds__(512,2) void k_gemm256(
  const u16* __restrict__ A, const u16* __restrict__ Bt, int K,
  int nrt, int nct, int ksplit, int klen, int SR, int SC,
  float* __restrict__ xio, float* __restrict__ Pf, u16* __restrict__ o0)
{
  int rt, ct, ks;
  job_map(blockIdx.x, gridDim.x, nrt, nct, ksplit, SR, SC, rt, ct, ks);

  __shared__ __align__(16) u16 lds[2][2][16384];
  int tid = threadIdx.x;
  int lane = tid & 63, wid = tid >> 6;
  int wm = wid >> 2, wn = wid & 3;
  int l15 = lane & 15, l4 = lane >> 4;
  int lsw = l15 & 7;
  int row0 = rt*256, col0 = ct*256;
  int kbase = ks*klen*64;

  const u16* aB = A  + (size_t)row0*K + kbase;
  const u16* bB = Bt + (size_t)col0*K + kbase;
  int rsub = tid >> 3;
  int gsw  = (lane & 7) ^ ((lane >> 3) & 7);

  f32x4 acc[8][4] = {};

  auto sgA = [&](int bf, int kt, int c){
    gld16(aB + (size_t)(c*64 + rsub)*K + kt*64 + gsw*8, &lds[bf][0][(c*512+tid)*8]);
  };
  auto sgB = [&](int bf, int kt, int c){
    gld16(bB + (size_t)(c*64 + rsub)*K + kt*64 + gsw*8, &lds[bf][1][(c*512+tid)*8]);
  };

  sgB(0,0,0); sgB(0,0,1); sgB(0,0,2); sgB(0,0,3);
  sgA(0,0,0); sgA(0,0,2); sgA(0,0,1); sgA(0,0,3);

  for (int t = 0; t < klen; ++t){
    int b = t & 1, nb = b ^ 1;
    bool hn = (t+1 < klen);
    const u16* Ab = lds[b][0];
    const u16* Bb = lds[b][1];
    s16x8 bfr[4][2];

    asm volatile("s_waitcnt vmcnt(2)" ::: "memory");
    __builtin_amdgcn_s_barrier();
    __builtin_amdgcn_sched_barrier(0);
    {
      s16x8 af[2][2];
      #pragma unroll
      for (int ii=0;ii<2;++ii)
        #pragma unroll
        for (int ksu=0;ksu<2;++ksu)
          af[ii][ksu] = *(const s16x8*)&Ab[(wm*128 + ii*16 + l15)*64 + (((ksu*4+l4)^lsw)<<3)];
      #pragma unroll
      for (int j=0;j<4;++j)
        #pragma unroll
        for (int ksu=0;ksu<2;++ksu)
          bfr[j][ksu] = *(const s16x8*)&Bb[(wn*64 + j*16 + l15)*64 + (((ksu*4+l4)^lsw)<<3)];
      if (hn){ sgB(nb, t+1, 0); sgB(nb, t+1, 1); }
      asm volatile("s_waitcnt lgkmcnt(0)" ::: "memory");
      __builtin_amdgcn_sched_barrier(0);
      __builtin_amdgcn_s_setprio(1);
      #pragma unroll
      for (int ii=0;ii<2;++ii)
        #pragma unroll
        for (int j=0;j<4;++j)
          #pragma unroll
          for (int ksu=0;ksu<2;++ksu)
            acc[ii][j] = __builtin_amdgcn_mfma_f32_16x16x32_bf16(af[ii][ksu], bfr[j][ksu], acc[ii][j], 0,0,0);
      __builtin_amdgcn_s_setprio(0);
      __builtin_amdgcn_s_barrier();
    }
    {
      s16x8 af[2][2];
      #pragma unroll
      for (int ii=0;ii<2;++ii)
        #pragma unroll
        for (int ksu=0;ksu<2;++ksu)
          af[ii][ksu] = *(const s16x8*)&Ab[(wm*128 + 32 + ii*16 + l15)*64 + (((ksu*4+l4)^lsw)<<3)];
      if (hn){ sgB(nb, t+1, 2); sgB(nb, t+1, 3); }
      asm volatile("s_waitcnt lgkmcnt(0)" ::: "memory");
      __builtin_amdgcn_sched_barrier(0);
      __builtin_amdgcn_s_setprio(1);
      #pragma unroll
      for (int ii=0;ii<2;++ii)
        #pragma unroll
        for (int j=0;j<4;++j)
          #pragma unroll
          for (int ksu=0;ksu<2;++ksu)
            acc[2+ii][j] = __builtin_amdgcn_mfma_f32_16x16x32_bf16(af[ii][ksu], bfr[j][ksu], acc[2+ii][j], 0,0,0);
      __builtin_amdgcn_s_setprio(0);
      __builtin_amdgcn_s_barrier();
    }
    if (hn) asm volatile("s_waitcnt vmcnt(4)" ::: "memory");
    else    asm volatile("s_waitcnt vmcnt(0)" ::: "memory");
    __builtin_amdgcn_s_barrier();
    __builtin_amdgcn_sched_barrier(0);
    {
      s16x8 af[2][2];
      #pragma unroll
      for (int ii=0;ii<2;++ii)
        #pragma unroll
        for (int ksu=0;ksu<2;++ksu)
          af[ii][ksu] = *(const s16x8*)&Ab[(wm*128 + 64 + ii*16 + l15)*64 + (((ksu*4+l4)^lsw)<<3)];
      if (hn){ sgA(nb, t+1, 0); sgA(nb, t+1, 2); }
      asm volatile("s_waitcnt lgkmcnt(0)" ::: "memory");
      __builtin_amdgcn_sched_barrier(0);
      __builtin_amdgcn_s_setprio(1);
      #pragma unroll
      for (int ii=0;ii<2;++ii)
        #pragma unroll
        for (int j=0;j<4;++j)
          #pragma unroll
          for (int ksu=0;ksu<2;++ksu)
            acc[4+ii][j] = __builtin_amdgcn_mfma_f32_16x16x32_bf16(af[ii][ksu], bfr[j][ksu], acc[4+ii][j], 0,0,0);
      __builtin_amdgcn_s_setprio(0);
      __builtin_amdgcn_s_barrier();
    }
    {
      s16x8 af[2][2];
      #pragma unroll
      for (int ii=0;ii<2;++ii)
        #pragma unroll
        for (int ksu=0;ksu<2;++ksu)
          af[ii][ksu] = *(const s16x8*)&Ab[(wm*128 + 96 + ii*16 + l15)*64 + (((ksu*4+l4)^lsw)<<3)];
      if (hn){ sgA(nb, t+1, 1); sgA(nb, t+1, 3); }
      asm volatile("s_waitcnt lgkmcnt(0)" ::: "memory");
      __builtin_amdgcn_sched_barrier(0);
      __builtin_amdgcn_s_setprio(1);
      #pragma unroll
      for (int ii=0;ii<2;++ii)
        #pragma unroll
        for (int j=0;j<4;++j)
          #pragma unroll
          for (int ksu=0;ksu<2;++ksu)
            acc[6+ii][j] = __builtin_amdgcn_mfma_f32_16x16x32_bf16(af[ii][ksu], bfr[j][ksu], acc[6+ii][j], 0,0,0);
      __builtin_amdgcn_s_setprio(0);
      __builtin_amdgcn_s_barrier();
    }
  }

  if constexpr (MODE == MODE_GATEUP){
    #pragma unroll
    for (int i=0;i<8;++i)
      #pragma unroll
      for (int j2=0;j2<4;j2+=2)
        #pragma unroll
        for (int r=0;r<4;++r){
          int row = row0 + wm*128 + i*16 + l4*4 + r;
          int cp  = col0 + wn*64 + j2*16 + l15;
          float gv = acc[i][j2][r], uv = acc[i][j2+1][r];
          float sg = 1.f/(1.f + __expf(-gv));
          int n = ((cp>>5)<<4) + (cp&15);
          o0[(size_t)row*8960 + n] = f2bf(sg*uv);
        }
  } else {
    #pragma unroll
    for (int i=0;i<8;++i)
      #pragma unroll
      for (int j=0;j<4;++j)
        #pragma unroll
        for (int r=0;r<4;++r){
          int row = row0 + wm*128 + i*16 + l4*4 + r;
          int c   = col0 + wn*64 + j*16 + l15;
          float v = acc[i][j][r];
          if (ks == 0) Pf[(size_t)row*1536 + c] = v;
          else         xio[(size_t)row*1536 + c] += v;
        }
  }
}

// ---------------- flash attention: QBLK=128, 48KB LDS, one resident round ----------------
__global__ __launch_bounds__(256) void k_attn(
  const u16* __restrict__ q, const u16* __restrict__ k, const u16* __restrict__ v,
  const u16* __restrict__ mtab, u16* __restrict__ attn)
{
  __shared__ __align__(16) u16 Qs[8192];    // 128 q-rows; wave w's 32 rows double as its P buffer after t=0
  __shared__ __align__(16) u16 Kd[2][4096];
  __shared__ __align__(16) u16 Vd[2][4096];
  int tid = threadIdx.x;
  int lane = tid & 63, w = tid >> 6;
  int qb = blockIdx.x;        // 0..15 (128 q-rows each)
  int bh = blockIdx.y;        // 0..47
  int b = bh / 24, hh = bh % 24, kv = hh / 6;
  int l15 = lane & 15, l4 = lane >> 4;
  int sw = l15 & 7;

  const u16* qhead = q + ((size_t)(b*24 + hh))*131072 + qb*8192;
  const u16* khead = k + ((size_t)(b*4  + kv))*131072;
  const u16* vhead = v + ((size_t)(b*4  + kv))*131072;
  const u16* mrow = mtab + b*2048;

  gld16(qhead + tid*8,        &Qs[tid*8]);
  gld16(qhead + (256+tid)*8,  &Qs[(256+tid)*8]);
  gld16(qhead + (512+tid)*8,  &Qs[(512+tid)*8]);
  gld16(qhead + (768+tid)*8,  &Qs[(768+tid)*8]);

  auto stage = [&](int bf, int kt){
    gld16(khead + kt*4096 + tid*8,       &Kd[bf][tid*8]);
    gld16(khead + kt*4096 + (256+tid)*8, &Kd[bf][(256+tid)*8]);
    gld16(vhead + kt*4096 + tid*8,       &Vd[bf][tid*8]);
    gld16(vhead + kt*4096 + (256+tid)*8, &Vd[bf][(256+tid)*8]);
  };
  stage(0, 0);

  s16x8 aq[2][2];                // [qa][half]
  f32x4 oacc[2][4] = {};
  float lsum[2] = {0.f, 0.f};
  u16* Pw = &Qs[w*2048];         // wave w's own 32 Q rows (register-resident after t=0)

  for (int t = 0; t < 32; ++t){
    asm volatile("s_waitcnt vmcnt(0)" ::: "memory");
    __builtin_amdgcn_s_barrier();
    __builtin_amdgcn_sched_barrier(0);
    if (t == 0){
      #pragma unroll
      for (int qa=0; qa<2; ++qa){
        int qrow = w*32 + qa*16 + l15;
        aq[qa][0] = *(const s16x8*)&Qs[qrow*64 + (( l4    ^ sw)<<3)];
        aq[qa][1] = *(const s16x8*)&Qs[qrow*64 + (((4+l4) ^ sw)<<3)];
      }
    }
    if (t+1 < 32) stage((t+1)&1, t+1);
    const u16* Kb = Kd[t&1];
    const u16* Vb = Vd[t&1];
    // swapped QK^T: lane holds q=l15 (within qa group), k = kn*16 + l4*4 + r
    f32x4 sk[2][4] = {};
    __builtin_amdgcn_s_setprio(1);
    #pragma unroll
    for (int kn=0; kn<4; ++kn){
      int krow = kn*16 + l15;
      s16x8 a0 = *(const s16x8*)&Kb[krow*64 + (( l4    ^ sw)<<3)];
      s16x8 a1 = *(const s16x8*)&Kb[krow*64 + (((4+l4) ^ sw)<<3)];
      #pragma unroll
      for (int qa=0; qa<2; ++qa){
        sk[qa][kn] = __builtin_amdgcn_mfma_f32_16x16x32_bf16(a0, aq[qa][0], sk[qa][kn], 0,0,0);
        sk[qa][kn] = __builtin_amdgcn_mfma_f32_16x16x32_bf16(a1, aq[qa][1], sk[qa][kn], 0,0,0);
      }
    }
    __builtin_amdgcn_s_setprio(0);
    // softmax: p = 2^(s + m')
    #pragma unroll
    for (int kn=0; kn<4; ++kn){
      u16x4 mv = *(const u16x4*)&mrow[t*64 + kn*16 + l4*4];
      #pragma unroll
      for (int qa=0; qa<2; ++qa){
        float p0 = aexp2(sk[qa][kn][0] + bf2f(mv.x));
        float p1 = aexp2(sk[qa][kn][1] + bf2f(mv.y));
        float p2 = aexp2(sk[qa][kn][2] + bf2f(mv.z));
        float p3 = aexp2(sk[qa][kn][3] + bf2f(mv.w));
        lsum[qa] += (p0 + p1) + (p2 + p3);
        u32x2 pk; pk.x = cvtpk(p0, p1); pk.y = cvtpk(p2, p3);
        int g = kn*2 + (l4>>1);
        *(u32x2*)&Pw[(qa*16 + l15)*64 + ((g ^ sw)<<3) + (l4&1)*4] = pk;
      }
    }
    // PV
    __builtin_amdgcn_s_setprio(1);
    #pragma unroll
    for (int ksu=0; ksu<2; ++ksu){
      s16x8 bv[4];
      #pragma unroll
      for (int dg=0; dg<4; ++dg)
        bv[dg] = *(const s16x8*)&Vb[(dg*16+l15)*64 + (((ksu*4+l4) ^ sw)<<3)];
      #pragma unroll
      for (int qa=0; qa<2; ++qa){
        s16x8 ap = *(const s16x8*)&Pw[(qa*16 + l15)*64 + (((ksu*4+l4) ^ sw)<<3)];
        #pragma unroll
        for (int dg=0; dg<4; ++dg)
          oacc[qa][dg] = __builtin_amdgcn_mfma_f32_16x16x32_bf16(ap, bv[dg], oacc[qa][dg], 0,0,0);
      }
    }
    __builtin_amdgcn_s_setprio(0);
  }
  #pragma unroll
  for (int qa=0; qa<2; ++qa){
    float t2 = lsum[qa];
    t2 += __shfl_xor(t2, 16, 64);
    t2 += __shfl_xor(t2, 32, 64);
    float invq[4];
    #pragma unroll
    for (int r=0;r<4;++r) invq[r] = 1.f / __shfl(t2, l4*4 + r, 64);
    #pragma unroll
    for (int dg=0;dg<4;++dg)
      #pragma unroll
      for (int r=0;r<4;++r){
        int token = b*2048 + qb*128 + w*32 + qa*16 + l4*4 + r;
        int col = hh*64 + dg*16 + l15;
        attn[(size_t)token*1536 + col] = f2bf(oacc[qa][dg][r] * invq[r]);
      }
  }
}

// ---------------- final GEMV ----------------
__global__ __launch_bounds__(256) void k_gemv(const u16* __restrict__ h2, const float* __restrict__ W2, const float* __restrict__ b2, float* __restrict__ out){
  int tid = threadIdx.x, lane = tid & 63, w = tid >> 6;
  int r = blockIdx.x*4 + w;
  const u16* hr = h2 + (size_t)r*1536;
  float s = 0.f;
  #pragma unroll
  for (int i=0;i<24;++i){ int c = lane + i*64; s += bf2f(hr[c]) * W2[c]; }
  #pragma unroll
  for (int off=32; off; off>>=1) s += __shfl_xor(s, off, 64);
  if (lane == 0) out[r] = s + b2[0];
}

extern "C" void kernel_launch(void* const* d_in, const int* in_sizes, int n_in,
                              void* d_out, int out_size, void* d_ws, size_t ws_size,
                              hipStream_t stream)
{
  const int*   ids   = (const int*)d_in[0];
  const float* mask  = (const float*)d_in[1];
  const float* embed = (const float*)d_in[2];
  const float* Wq    = (const float*)d_in[3];
  const float* bq    = (const float*)d_in[4];
  const float* Wk    = (const float*)d_in[5];
  const float* bk    = (const float*)d_in[6];
  const float* Wv    = (const float*)d_in[7];
  const float* bv    = (const float*)d_in[8];
  const float* Wo    = (const float*)d_in[9];
  const float* ln1   = (const float*)d_in[10];
  const float* ln2   = (const float*)d_in[11];
  const float* Wg    = (const float*)d_in[12];
  const float* Wu    = (const float*)d_in[13];
  const float* Wd    = (const float*)d_in[14];
  const float* nw    = (const float*)d_in[15];
  const float* W1    = (const float*)d_in[16];
  const float* b1    = (const float*)d_in[17];
  const float* W2    = (const float*)d_in[18];
  const float* b2    = (const float*)d_in[19];
  const float* cosT  = (const float*)d_in[20];
  const float* sinT  = (const float*)d_in[21];

  char* ws = (char*)d_ws;
  float* x   = (float*)(ws + 0);            // 4096x1536 f32
  u16* h     = (u16*)(ws + 25165824);       // 4096x1536 bf16
  u16* qb_   = (u16*)(ws + 37748736);       // (2,24) heads x 131072 u16, tiled+swizzled
  u16* kb_   = (u16*)(ws + 50331648);       // (2,4) kv-heads x 131072 u16, tiled+swizzled
  u16* vb_   = (u16*)(ws + 52428800);       // (2,4) kv-heads x 131072 u16, V^T tiled+swizzled
  u16* attn  = (u16*)(ws + 54525952);       // 4096x1536 bf16 (also final gelu h2)
  u16* g     = (u16*)(ws + 67108864);       // 4096x8960 bf16
  u16* qkvt  = (u16*)(ws + 140509184);      // 2048x1536 bf16
  u16* wot   = (u16*)(ws + 146800640);      // 1536x1536 bf16
  u16* gut   = (u16*)(ws + 151519232);      // 17920x1536 bf16
  u16* wdt   = (u16*)(ws + 206569472);      // 1536x8960 bf16
  u16* mtab  = (u16*)(ws + 234094592);      // 2x2048 bf16 additive mask
  float* Pf  = (float*)(ws + 37748736);     // down split-K partial (overlays q/k/v/attn, dead then)
  (void)in_sizes; (void)n_in; (void)out_size; (void)ws_size;

  k_embed<<<4096, 256, 0, stream>>>(ids, embed, x);
  k_mask<<<16, 256, 0, stream>>>(mask, mtab);
  for (int l = 0; l < 8; ++l){
    k_cvt_layer<<<dim3(3360,7), 256, 0, stream>>>(
      Wq + (size_t)l*1536*1536, Wk + (size_t)l*1536*256, Wv + (size_t)l*1536*256,
      Wo + (size_t)l*1536*1536, Wg + (size_t)l*1536*8960, Wu + (size_t)l*1536*8960,
      Wd + (size_t)l*8960*1536, qkvt, wot, gut, wdt);
    if (l == 0) k_rms<<<4096, 256, 0, stream>>>(x, ln1, h);
    else        k_rms_add<<<4096, 256, 0, stream>>>(x, Pf, ln1 + l*1536, h);
    k_gemm<MODE_QKV><<<512, 256, 0, stream>>>(h, qkvt, 1536, 32, 16, 1, 1536, 8, 4,
        bq + l*1536, bk + l*256, bv + l*256, nullptr, nullptr, cosT, sinT, qb_, kb_, vb_);
    k_attn<<<dim3(16,48), 256, 0, stream>>>(qb_, kb_, vb_, mtab, attn);
    k_gemm<MODE_WO><<<384, 256, 0, stream>>>(attn, wot, 1536, 32, 12, 1, 1536, 8, 4,
        nullptr, nullptr, nullptr, x, nullptr, nullptr, nullptr, nullptr, nullptr, nullptr);
    k_rms<<<4096, 256, 0, stream>>>(x, ln2 + l*1536, h);
    k_gemm256<MODE_GATEUP><<<1120, 512, 0, stream>>>(h, gut, 1536, 16, 70, 1, 24, 8, 10,
        nullptr, nullptr, g);
    k_gemm256<MODE_DOWN><<<192, 512, 0, stream>>>(g, wdt, 8960, 16, 6, 2, 70, 4, 6,
        x, Pf, nullptr);
  }
  k_cvt_one<<<576, 256, 0, stream>>>(W1, wot);
  k_rms_add<<<4096, 256, 0, stream>>>(x, Pf, nw, h);
  k_gemm<MODE_W1><<<384, 256, 0, stream>>>(h, wot, 1536, 32, 12, 1, 1536, 8, 4,
      b1, nullptr, nullptr, nullptr, nullptr, nullptr, nullptr, attn, nullptr, nullptr);
  k_gemv<<<1024, 256, 0, stream>>>(attn, W2, b2, (float*)d_out);
}